// Round 12
// baseline (109.727 us; speedup 1.0000x reference)
//
#include <hip/hip_runtime.h>
#include <hip/hip_fp16.h>
#include <math.h>

// B=4, C=64, H=W=128, O=64, K=3, pad=1, stride=1
// Round-25: R17 base (green 97.2us; R18/R23/R24 ILP attacks all null) + ONE delta:
// SPLIT-K ACROSS WAVE GROUPS. k_fused: 512 blocks x 1024 thr = 16 waves; group A
// (t<512) does K-half kb=0, group B kb=1 -> per-wave work halves, total waves
// 4096 -> 8192 = 8 waves/SIMD (2x latency hiding; the ILP nulls showed per-wave
// duty ~7%, so TLP is the binding constraint). Phase 1 splits kb 0-8/9-17 with
// f32x4 LDS partial reduction (16KB); phase 2 per-group kb plane (4 ds_read +
// 4 MFMA per kk); acc reduction reuses dead patch buffer (32KB). LDS 63.7KB.
// __launch_bounds__(1024,8) caps VGPR<=64 (R21 measured 60 w/ more state) ->
// 2 blocks/CU. f32 accumulation reorder only; absmax margin 3x.
// Known harness floor ~52us (268MB ws re-poison fill @ ~6TB/s + restores) inside dur_us.
// ws: xh 8.39 MB + wtF + pgwF (~8.5 MB)

typedef __attribute__((ext_vector_type(8))) short short8;     // 8 f16 bit-patterns (A/B frag)
typedef __attribute__((ext_vector_type(8))) _Float16 f16x8;   // MFMA A/B frag (4 VGPRs)
typedef __attribute__((ext_vector_type(4))) float f32x4;      // C/D frag

#define PSTR 2088   // padded plane stride in shorts (260 pos * 8 ch + 8 pad)

__device__ __forceinline__ unsigned short f2h(float f) {   // RNE f32->f16
    union { __half h; unsigned short s; } v; v.h = __float2half_rn(f); return v.s;
}
__device__ __forceinline__ f16x8 s2f(short8 s) {
    union { short8 s; f16x8 f; } u; u.s = s; return u.f;
}
__device__ __forceinline__ __half2 u2h2(unsigned u) {
    union { unsigned u; __half2 h; } v; v.u = u; return v.h;
}
__device__ __forceinline__ unsigned uget(const uint4& v, int p) {
    return p == 0 ? v.x : p == 1 ? v.y : p == 2 ? v.z : v.w;
}

// ---------------- K0: merged prep: NCHW->NHWC f16 transpose  +  weight pack (exact R17) ----------------
__global__ __launch_bounds__(256) void k_prep(const float* __restrict__ x,
                                              unsigned short* __restrict__ xh,
                                              const float* __restrict__ weight,
                                              const float* __restrict__ pg_w,
                                              unsigned short* __restrict__ wtF,
                                              unsigned short* __restrict__ pgwF) {
    __shared__ float tile[64][33];
    int bid = blockIdx.x;
    int t = threadIdx.x;
    if (bid < 2048) {
        int b = bid >> 9, h = (bid >> 2) & 127, w0 = (bid & 3) * 32;
        for (int idx = t; idx < 2048; idx += 256) {
            int c = idx >> 5, w = idx & 31;
            tile[c][w] = x[((b * 64 + c) * 128 + h) * 128 + w0 + w];
        }
        __syncthreads();
        {
            int wl = t >> 3, c0 = (t & 7) * 8;
            short8 v;
#pragma unroll
            for (int e = 0; e < 8; ++e) v[e] = (short)f2h(tile[c0 + e][wl]);
            *(short8*)&xh[(((size_t)b * 128 + h) * 128 + w0 + wl) * 64 + c0] = v;
        }
    } else {
        int idx = (bid - 2048) * 256 + t;
        if (idx < 36864) {
            int e = idx & 7, l = (idx >> 3) & 63, grp = idx >> 9;   // grp 0..71
            int nt = grp & 3, kb = (grp >> 2) & 1, kk = grp >> 3;
            int ln = l & 15, quad = l >> 4;
            int o = nt * 16 + ln;
            int c = kb * 32 + quad * 8 + e;
            wtF[idx] = f2h(weight[(o * 64 + c) * 9 + kk]);
        }
        int i2 = idx - 36864;
        if (i2 >= 0 && i2 < 18432) {
            int e = i2 & 7, l = (i2 >> 3) & 63, grp = i2 >> 9;      // grp 0..35
            int tl = grp & 1, kb = grp >> 1;
            int ln = l & 15, quad = l >> 4;
            int p = tl * 16 + ln;
            int k = kb * 32 + quad * 8 + e;
            float v = 0.f;
            if (p < 27) {
                int q = k >> 6, c = k & 63;
                v = pg_w[(p * 64 + c) * 9 + q];
            }
            pgwF[i2] = f2h(v);
        }
    }
}

// ---------------- K2: fused kernel, 8x16 tile, SPLIT-K: 16 waves = 2 groups x 8 ----------------
// 512 blocks (b x 16 x 8) x 1024 threads. Group g = t>>9 handles K-half kb=g.
__global__ __launch_bounds__(1024, 8) void k_fused(const unsigned short* __restrict__ xh,
                                                   const unsigned short* __restrict__ pgwF,
                                                   const float* __restrict__ pg_b,
                                                   const unsigned short* __restrict__ wtF,
                                                   const float* __restrict__ bias,
                                                   float* __restrict__ out) {
    __shared__ unsigned short patch[8 * PSTR];   // 32.6 KB [cg][pos][8ch]; reused for acc-red
    __shared__ float P_s[27 * 129];              // 13.9 KB [param][px], stride 129
    __shared__ f32x4 redv[1024];                 // 16 KB phase-1 partials from group B

    int bid = blockIdx.x;
    int b  = bid >> 7;
    int h0 = ((bid >> 3) & 15) * 8;
    int w0 = (bid & 7) * 16;
    int t = threadIdx.x;
    int g  = t >> 9;                     // 0 = group A, 1 = group B
    int tt = t & 511;
    int base_y = h0 - 2, base_x = w0 - 2;
    const unsigned short* xbb = xh + (size_t)b * 16384 * 64;

    // ---- phase 0: stage patch from xh; 2080 b128 chunks, coalesced (1024 threads) ----
    for (int i = t; i < 2080; i += 1024) {
        int yy = i / 160;                 // 8 chunks per 20-col row
        int r  = i - yy * 160;
        int xx = r >> 3;
        int cgr = r & 7;
        int gy = base_y + yy, gx = base_x + xx;
        int pos = yy * 20 + xx;
        short8 v = (short8)0;
        if (((unsigned)gy < 128u) && ((unsigned)gx < 128u))
            v = *(const short8*)&xbb[(gy * 128 + gx) * 64 + cgr * 8];
        *(short8*)&patch[cgr * PSTR + pos * 8] = v;
    }
    __syncthreads();

    int l = tt & 63, wv = tt >> 6;       // wv = 0..7 = pixel row (per group)
    int quad = l >> 4, ln = l & 15;
    int px = wv * 16 + ln;               // px = row-major pixel id (row wv, col ln)
    int hh = h0 + wv, ww = w0 + ln;

    // ---- phase 1: offset conv MFMA (M=128,N=32,K=576) split: group g does kb=g*9..g*9+8 ----
    {
        f32x4 o0 = {0.f, 0.f, 0.f, 0.f}, o1 = {0.f, 0.f, 0.f, 0.f};
#pragma unroll
        for (int j = 0; j < 9; ++j) {
            int kb = g * 9 + j;
            int q = kb >> 1;
            int kh = q / 3, kw = q - 3 * (q / 3);
            short8 b0 = *(const short8*)&pgwF[(kb * 2 + 0) * 512 + l * 8];   // lane*16B
            short8 b1 = *(const short8*)&pgwF[(kb * 2 + 1) * 512 + l * 8];
            int aoff = (wv + kh + 1) * 20 + (ln + kw + 1);
            int cg = (kb & 1) * 4 + quad;
            short8 af = *(const short8*)&patch[cg * PSTR + aoff * 8];
            o0 = __builtin_amdgcn_mfma_f32_16x16x32_f16(s2f(af), s2f(b0), o0, 0, 0, 0);
            o1 = __builtin_amdgcn_mfma_f32_16x16x32_f16(s2f(af), s2f(b1), o1, 0, 0, 0);
        }
        if (g == 1) {
            redv[tt * 2 + 0] = o0;
            redv[tt * 2 + 1] = o1;
        }
        __syncthreads();
        if (g == 0) {
            o0 = o0 + redv[tt * 2 + 0];
            o1 = o1 + redv[tt * 2 + 1];
#pragma unroll
            for (int tile = 0; tile < 2; ++tile) {
                int p = tile * 16 + ln;
                f32x4 a = tile ? o1 : o0;
                if (p < 27) {
                    float bo = pg_b[p];
#pragma unroll
                    for (int i = 0; i < 4; ++i) {
                        int wpx = wv * 16 + quad * 4 + i;
                        float v = a[i] + bo;
                        if (p >= 18) v = 1.f / (1.f + expf(-v));
                        P_s[p * 129 + wpx] = v;
                    }
                }
            }
        }
    }
    __syncthreads();

    // ---- phase 2: sampling + main GEMM; group g handles its K-half (kb=g) only ----
    f32x4 acc[4];
#pragma unroll
    for (int nt = 0; nt < 4; ++nt) acc[nt] = (f32x4){0.f, 0.f, 0.f, 0.f};

    int qbase = quad * PSTR + g * 4 * PSTR;  // per-thread constant plane base (incl. K-half)

    for (int kk = 0; kk < 9; ++kk) {
        // B fragments for this group's kb: coalesced lane*16B loads (L1/L2-hot)
        short8 bfr[4];
#pragma unroll
        for (int nt = 0; nt < 4; ++nt)
            bfr[nt] = *(const short8*)&wtF[((kk * 2 + g) * 4 + nt) * 512 + l * 8];

        // bilinear params from LDS (stride 129) — identical for both groups
        int ki = kk / 3, kj = kk - 3 * (kk / 3);
        float dyv = P_s[(2 * kk) * 129 + px];
        float dxv = P_s[(2 * kk + 1) * 129 + px];
        float m   = P_s[(18 + kk) * 129 + px];
        float ys = (float)(hh - 1 + ki) + dyv;
        float xs = (float)(ww - 1 + kj) + dxv;
        float y0f = floorf(ys), x0f = floorf(xs);
        int y0 = (int)y0f, x0 = (int)x0f;
        float ly = ys - y0f, lx = xs - x0f;
        float v0y = ((unsigned)y0 < 128u) ? 1.f : 0.f;
        float v1y = ((unsigned)(y0 + 1) < 128u) ? 1.f : 0.f;
        float v0x = ((unsigned)x0 < 128u) ? 1.f : 0.f;
        float v1x = ((unsigned)(x0 + 1) < 128u) ? 1.f : 0.f;
        float w00 = (1.f - ly) * (1.f - lx) * v0y * v0x * m;
        float w01 = (1.f - ly) * lx * v0y * v1x * m;
        float w10 = ly * (1.f - lx) * v1y * v0x * m;
        float w11 = ly * lx * v1y * v1x * m;
        int ly0 = y0 - base_y, lx0 = x0 - base_x;
        bool inp = ((unsigned)ly0 < 12u) && ((unsigned)lx0 < 18u);

        uint4 r0, r1, r2, r3;
        if (inp) {
            int base = qbase + (ly0 * 20 + lx0) * 8;   // corners = imm offsets off one base
            r0 = *(const uint4*)&patch[base];
            r1 = *(const uint4*)&patch[base + 8];
            r2 = *(const uint4*)&patch[base + 160];
            r3 = *(const uint4*)&patch[base + 168];
        } else {   // rare (|offset| >= 1): direct xh reads, clamped corners
            int y0c = min(max(y0, 0), 127), y1c = min(max(y0 + 1, 0), 127);
            int x0c = min(max(x0, 0), 127), x1c = min(max(x0 + 1, 0), 127);
            int base00 = (y0c * 128 + x0c) * 64;
            int dxo = (x1c - x0c) * 64, dyo = (y1c - y0c) * 8192;
            int c0 = g * 32 + quad * 8;
            r0 = *(const uint4*)&xbb[base00 + c0];
            r1 = *(const uint4*)&xbb[base00 + dxo + c0];
            r2 = *(const uint4*)&xbb[base00 + dyo + c0];
            r3 = *(const uint4*)&xbb[base00 + dyo + dxo + c0];
        }

        // packed-f16 bilinear: 2 channels per step; pure v_pk_mul/fma_f16
        __half2 W00 = __float2half2_rn(w00), W01 = __float2half2_rn(w01);
        __half2 W10 = __float2half2_rn(w10), W11 = __float2half2_rn(w11);
        union { unsigned u[4]; f16x8 f; } afu;
#pragma unroll
        for (int p = 0; p < 4; ++p) {
            __half2 v = __hmul2(W00, u2h2(uget(r0, p)));
            v = __hfma2(W01, u2h2(uget(r1, p)), v);
            v = __hfma2(W10, u2h2(uget(r2, p)), v);
            v = __hfma2(W11, u2h2(uget(r3, p)), v);
            afu.u[p] = *(unsigned*)&v;
        }

#pragma unroll
        for (int nt = 0; nt < 4; ++nt)
            acc[nt] = __builtin_amdgcn_mfma_f32_16x16x32_f16(afu.f, s2f(bfr[nt]), acc[nt], 0, 0, 0);
    }

    // ---- acc reduction: group B -> patch (dead now), group A adds + epilogue ----
    __syncthreads();                         // everyone done reading patch
    f32x4* red2 = (f32x4*)patch;             // 512 * 4 * 16B = 32 KB
    if (g == 1) {
#pragma unroll
        for (int nt = 0; nt < 4; ++nt) red2[tt * 4 + nt] = acc[nt];
    }
    __syncthreads();
    if (g == 0) {
        int ehh = h0 + wv, eww = w0 + quad * 4;
#pragma unroll
        for (int nt = 0; nt < 4; ++nt) {
            f32x4 s = acc[nt] + red2[tt * 4 + nt];
            int o = nt * 16 + ln;
            float bo = bias[o];
            float4 v;
            v.x = s[0] + bo; v.y = s[1] + bo;
            v.z = s[2] + bo; v.w = s[3] + bo;
            *(float4*)&out[((size_t)b * 64 + o) * 16384 + ehh * 128 + eww] = v;
        }
    }
}

extern "C" void kernel_launch(void* const* d_in, const int* in_sizes, int n_in,
                              void* d_out, int out_size, void* d_ws, size_t ws_size,
                              hipStream_t stream) {
    const float* x      = (const float*)d_in[0];
    const float* weight = (const float*)d_in[1];
    const float* bias   = (const float*)d_in[2];
    const float* pg_w   = (const float*)d_in[3];
    const float* pg_b   = (const float*)d_in[4];
    float* out = (float*)d_out;

    unsigned short* xhB  = (unsigned short*)d_ws;        // 4*16384*64 f16 (8.39 MB)
    unsigned short* wtF  = xhB + (size_t)4 * 16384 * 64; // 36,864 f16 (fragment order)
    unsigned short* pgwF = wtF + 36864;                  // 18,432 f16 (fragment order)

    k_prep<<<2264, 256, 0, stream>>>(x, xhB, weight, pg_w, wtF, pgwF);
    k_fused<<<512, 1024, 0, stream>>>(xhB, pgwF, pg_b, wtF, bias, out);
}

// Round 13
// 97.932 us; speedup vs baseline: 1.1204x; 1.1204x over previous
//
#include <hip/hip_runtime.h>
#include <hip/hip_fp16.h>
#include <math.h>

// B=4, C=64, H=W=128, O=64, K=3, pad=1, stride=1
// Round-26 FINAL: restore R17 verbatim — the best harness-verified kernel (97.2us).
// Session ledger: R14-R16 VALU cuts (packed-f16 bilinear, cg-major LDS, -4.5us),
// R17 prep merge (-2.5us). Subsequent attacks all null or negative:
//   R18/R23/R24 ILP (unroll / branchless corners / hand pipeline): null — phase-2
//     latency not recoverable by intra-wave scheduling at HIP source level.
//   R20 cooperative single-kernel: FAILED correctness (grid.sync stale xh cross-XCD).
//   R21 direct-NCHW staging: -16us regression (uncoalesced gathers, LDS write conflicts).
//   R25 split-K 16-wave TLP: collapse via VGPR/AGPR spill (8 waves/SIMD needs <=64 regs
//     incl. 16 MFMA accumulators — structurally infeasible for this algorithm).
// Structural floor: fill ~45us (75% HBM peak) + harness restores ~21us + k_prep ~5us
// (BW-bound) + k_fused ~26us (latency plateau at 4 waves/SIMD; pipe-busy floor
// ~10-12us; 4096 waves fixed by 16px x 64out per-wave MFMA tile).
// ws: xh 8.39 MB + wtF + pgwF (~8.5 MB)

typedef __attribute__((ext_vector_type(8))) short short8;     // 8 f16 bit-patterns (A/B frag)
typedef __attribute__((ext_vector_type(8))) _Float16 f16x8;   // MFMA A/B frag (4 VGPRs)
typedef __attribute__((ext_vector_type(4))) float f32x4;      // C/D frag

#define PSTR 2088   // padded plane stride in shorts (260 pos * 8 ch + 8 pad)

__device__ __forceinline__ unsigned short f2h(float f) {   // RNE f32->f16
    union { __half h; unsigned short s; } v; v.h = __float2half_rn(f); return v.s;
}
__device__ __forceinline__ f16x8 s2f(short8 s) {
    union { short8 s; f16x8 f; } u; u.s = s; return u.f;
}
__device__ __forceinline__ __half2 u2h2(unsigned u) {
    union { unsigned u; __half2 h; } v; v.u = u; return v.h;
}
__device__ __forceinline__ unsigned h22u(__half2 h) {
    union { __half2 h; unsigned u; } v; v.h = h; return v.u;
}
__device__ __forceinline__ unsigned uget(const uint4& v, int p) {
    return p == 0 ? v.x : p == 1 ? v.y : p == 2 ? v.z : v.w;
}

// ---------------- K0: merged prep: NCHW->NHWC f16 transpose  +  weight pack ----------------
// blocks 0..2047: transpose body. blocks 2048..2263: pack body.
__global__ __launch_bounds__(256) void k_prep(const float* __restrict__ x,
                                              unsigned short* __restrict__ xh,
                                              const float* __restrict__ weight,
                                              const float* __restrict__ pg_w,
                                              unsigned short* __restrict__ wtF,
                                              unsigned short* __restrict__ pgwF) {
    __shared__ float tile[64][33];
    int bid = blockIdx.x;
    int t = threadIdx.x;
    if (bid < 2048) {
        int b = bid >> 9, h = (bid >> 2) & 127, w0 = (bid & 3) * 32;
        for (int idx = t; idx < 2048; idx += 256) {
            int c = idx >> 5, w = idx & 31;
            tile[c][w] = x[((b * 64 + c) * 128 + h) * 128 + w0 + w];
        }
        __syncthreads();
        {
            int wl = t >> 3, c0 = (t & 7) * 8;
            short8 v;
#pragma unroll
            for (int e = 0; e < 8; ++e) v[e] = (short)f2h(tile[c0 + e][wl]);
            *(short8*)&xh[(((size_t)b * 128 + h) * 128 + w0 + wl) * 64 + c0] = v;
        }
    } else {
        int idx = (bid - 2048) * 256 + t;
        if (idx < 36864) {
            int e = idx & 7, l = (idx >> 3) & 63, grp = idx >> 9;   // grp 0..71
            int nt = grp & 3, kb = (grp >> 2) & 1, kk = grp >> 3;
            int ln = l & 15, quad = l >> 4;
            int o = nt * 16 + ln;
            int c = kb * 32 + quad * 8 + e;
            wtF[idx] = f2h(weight[(o * 64 + c) * 9 + kk]);
        }
        int i2 = idx - 36864;
        if (i2 >= 0 && i2 < 18432) {
            int e = i2 & 7, l = (i2 >> 3) & 63, grp = i2 >> 9;      // grp 0..35
            int tl = grp & 1, kb = grp >> 1;
            int ln = l & 15, quad = l >> 4;
            int p = tl * 16 + ln;
            int k = kb * 32 + quad * 8 + e;
            float v = 0.f;
            if (p < 27) {
                int q = k >> 6, c = k & 63;
                v = pg_w[(p * 64 + c) * 9 + q];
            }
            pgwF[i2] = f2h(v);
        }
    }
}

// ---------------- K2: fused offset-conv + deformable conv, 8x16 tile ----------------
// 512 blocks (b x 16 x 8), tile = 8 rows x 16 cols. 512 threads = 8 waves; wave w = row w.
__global__ __launch_bounds__(512) void k_fused(const unsigned short* __restrict__ xh,
                                               const unsigned short* __restrict__ pgwF,
                                               const float* __restrict__ pg_b,
                                               const unsigned short* __restrict__ wtF,
                                               const float* __restrict__ bias,
                                               float* __restrict__ out) {
    __shared__ unsigned short patch[8 * PSTR];   // 32.6 KB [cg][pos][8ch], plane pad +8
    __shared__ float P_s[27 * 129];              // 13.9 KB [param][px], stride 129

    int bid = blockIdx.x;
    int b  = bid >> 7;
    int h0 = ((bid >> 3) & 15) * 8;
    int w0 = (bid & 7) * 16;
    int t = threadIdx.x;
    int base_y = h0 - 2, base_x = w0 - 2;
    const unsigned short* xbb = xh + (size_t)b * 16384 * 64;

    // ---- phase 0: stage patch from xh; 2080 b128 chunks, coalesced ----
    for (int i = t; i < 2080; i += 512) {
        int yy = i / 160;                 // 8 chunks per 20-col row
        int r  = i - yy * 160;
        int xx = r >> 3;
        int cg = r & 7;
        int gy = base_y + yy, gx = base_x + xx;
        int pos = yy * 20 + xx;
        short8 v = (short8)0;
        if (((unsigned)gy < 128u) && ((unsigned)gx < 128u))
            v = *(const short8*)&xbb[(gy * 128 + gx) * 64 + cg * 8];
        *(short8*)&patch[cg * PSTR + pos * 8] = v;
    }
    __syncthreads();

    int l = t & 63, w = t >> 6;          // w = 0..7 = pixel row
    int quad = l >> 4, ln = l & 15;
    int px = w * 16 + ln;                // px = row-major pixel id (row w, col ln)
    int hh = h0 + w, ww = w0 + ln;

    // ---- phase 1: offset conv MFMA (M=128, N=32, K=576), B from pgwF coalesced ----
    {
        f32x4 o0 = {0.f, 0.f, 0.f, 0.f}, o1 = {0.f, 0.f, 0.f, 0.f};
#pragma unroll
        for (int kb = 0; kb < 18; ++kb) {
            int q = kb >> 1;
            int kh = q / 3, kw = q - 3 * (q / 3);
            short8 b0 = *(const short8*)&pgwF[(kb * 2 + 0) * 512 + l * 8];   // lane*16B
            short8 b1 = *(const short8*)&pgwF[(kb * 2 + 1) * 512 + l * 8];
            int aoff = (w + kh + 1) * 20 + (ln + kw + 1);
            int cg = (kb & 1) * 4 + quad;
            short8 af = *(const short8*)&patch[cg * PSTR + aoff * 8];
            o0 = __builtin_amdgcn_mfma_f32_16x16x32_f16(s2f(af), s2f(b0), o0, 0, 0, 0);
            o1 = __builtin_amdgcn_mfma_f32_16x16x32_f16(s2f(af), s2f(b1), o1, 0, 0, 0);
        }
#pragma unroll
        for (int tile = 0; tile < 2; ++tile) {
            int p = tile * 16 + ln;
            f32x4 a = tile ? o1 : o0;
            if (p < 27) {
                float bo = pg_b[p];
#pragma unroll
                for (int i = 0; i < 4; ++i) {
                    int wpx = w * 16 + quad * 4 + i;
                    float v = a[i] + bo;
                    if (p >= 18) v = 1.f / (1.f + expf(-v));
                    P_s[p * 129 + wpx] = v;
                }
            }
        }
    }
    __syncthreads();

    // ---- phase 2: sampling + main GEMM (M=128,N=64,K=576), B from wtF coalesced ----
    f32x4 acc[4];
#pragma unroll
    for (int nt = 0; nt < 4; ++nt) acc[nt] = (f32x4){0.f, 0.f, 0.f, 0.f};

    int qbase = quad * PSTR;             // per-thread constant plane base

    for (int kk = 0; kk < 9; ++kk) {
        // B fragments: coalesced lane*16B loads (L1/L2-hot)
        short8 bfr[2][4];
#pragma unroll
        for (int kb = 0; kb < 2; ++kb)
#pragma unroll
            for (int nt = 0; nt < 4; ++nt)
                bfr[kb][nt] = *(const short8*)&wtF[((kk * 2 + kb) * 4 + nt) * 512 + l * 8];

        // bilinear params from LDS (stride 129)
        int ki = kk / 3, kj = kk - 3 * (kk / 3);
        float dyv = P_s[(2 * kk) * 129 + px];
        float dxv = P_s[(2 * kk + 1) * 129 + px];
        float m   = P_s[(18 + kk) * 129 + px];
        float ys = (float)(hh - 1 + ki) + dyv;
        float xs = (float)(ww - 1 + kj) + dxv;
        float y0f = floorf(ys), x0f = floorf(xs);
        int y0 = (int)y0f, x0 = (int)x0f;
        float ly = ys - y0f, lx = xs - x0f;
        float v0y = ((unsigned)y0 < 128u) ? 1.f : 0.f;
        float v1y = ((unsigned)(y0 + 1) < 128u) ? 1.f : 0.f;
        float v0x = ((unsigned)x0 < 128u) ? 1.f : 0.f;
        float v1x = ((unsigned)(x0 + 1) < 128u) ? 1.f : 0.f;
        float w00 = (1.f - ly) * (1.f - lx) * v0y * v0x * m;
        float w01 = (1.f - ly) * lx * v0y * v1x * m;
        float w10 = ly * (1.f - lx) * v1y * v0x * m;
        float w11 = ly * lx * v1y * v1x * m;
        int ly0 = y0 - base_y, lx0 = x0 - base_x;
        bool inp = ((unsigned)ly0 < 12u) && ((unsigned)lx0 < 18u);

        uint4 r[2][4];
        if (inp) {
            int pb = qbase + (ly0 * 20 + lx0) * 8;   // one base; corners = imm offsets
#pragma unroll
            for (int kb = 0; kb < 2; ++kb) {
                int base = pb + kb * 4 * PSTR;       // kb term folds to imm in ds_read
                r[kb][0] = *(const uint4*)&patch[base];
                r[kb][1] = *(const uint4*)&patch[base + 8];
                r[kb][2] = *(const uint4*)&patch[base + 160];
                r[kb][3] = *(const uint4*)&patch[base + 168];
            }
        } else {   // rare (|offset| >= 1): direct xh reads, clamped corners
            int y0c = min(max(y0, 0), 127), y1c = min(max(y0 + 1, 0), 127);
            int x0c = min(max(x0, 0), 127), x1c = min(max(x0 + 1, 0), 127);
            int base00 = (y0c * 128 + x0c) * 64;
            int dxo = (x1c - x0c) * 64, dyo = (y1c - y0c) * 8192;
#pragma unroll
            for (int kb = 0; kb < 2; ++kb) {
                int c0 = kb * 32 + quad * 8;
                r[kb][0] = *(const uint4*)&xbb[base00 + c0];
                r[kb][1] = *(const uint4*)&xbb[base00 + dxo + c0];
                r[kb][2] = *(const uint4*)&xbb[base00 + dyo + c0];
                r[kb][3] = *(const uint4*)&xbb[base00 + dyo + dxo + c0];
            }
        }

        // packed-f16 bilinear: 2 channels per step; pure v_pk_mul/fma_f16, no unpack/repack
        __half2 W00 = __float2half2_rn(w00), W01 = __float2half2_rn(w01);
        __half2 W10 = __float2half2_rn(w10), W11 = __float2half2_rn(w11);
        f16x8 af[2];
#pragma unroll
        for (int kb = 0; kb < 2; ++kb) {
            union { unsigned u[4]; f16x8 f; } afu;
#pragma unroll
            for (int p = 0; p < 4; ++p) {
                __half2 v = __hmul2(W00, u2h2(uget(r[kb][0], p)));
                v = __hfma2(W01, u2h2(uget(r[kb][1], p)), v);
                v = __hfma2(W10, u2h2(uget(r[kb][2], p)), v);
                v = __hfma2(W11, u2h2(uget(r[kb][3], p)), v);
                afu.u[p] = h22u(v);
            }
            af[kb] = afu.f;
        }

#pragma unroll
        for (int kb = 0; kb < 2; ++kb)
#pragma unroll
            for (int nt = 0; nt < 4; ++nt)
                acc[nt] = __builtin_amdgcn_mfma_f32_16x16x32_f16(af[kb], s2f(bfr[kb][nt]), acc[nt], 0, 0, 0);
    }

    // ---- epilogue: lane's 4 D-rows per nt = row w, cols quad*4..+3 -> float4 ----
    int ehh = h0 + w, eww = w0 + quad * 4;
#pragma unroll
    for (int nt = 0; nt < 4; ++nt) {
        int o = nt * 16 + ln;
        float bo = bias[o];
        float4 v;
        v.x = acc[nt][0] + bo; v.y = acc[nt][1] + bo;
        v.z = acc[nt][2] + bo; v.w = acc[nt][3] + bo;
        *(float4*)&out[((size_t)b * 64 + o) * 16384 + ehh * 128 + eww] = v;
    }
}

extern "C" void kernel_launch(void* const* d_in, const int* in_sizes, int n_in,
                              void* d_out, int out_size, void* d_ws, size_t ws_size,
                              hipStream_t stream) {
    const float* x      = (const float*)d_in[0];
    const float* weight = (const float*)d_in[1];
    const float* bias   = (const float*)d_in[2];
    const float* pg_w   = (const float*)d_in[3];
    const float* pg_b   = (const float*)d_in[4];
    float* out = (float*)d_out;

    unsigned short* xhB  = (unsigned short*)d_ws;        // 4*16384*64 f16 (8.39 MB)
    unsigned short* wtF  = xhB + (size_t)4 * 16384 * 64; // 36,864 f16 (fragment order)
    unsigned short* pgwF = wtF + 36864;                  // 18,432 f16 (fragment order)

    k_prep<<<2264, 256, 0, stream>>>(x, xhB, weight, pg_w, wtF, pgwF);
    k_fused<<<512, 512, 0, stream>>>(xhB, pgwF, pg_b, wtF, bias, out);
}